// Round 1
// baseline (2140.149 us; speedup 1.0000x reference)
//
#include <hip/hip_runtime.h>
#include <hip/hip_bf16.h>

// FP4 fake-quant MLP: out = Q(relu(Q(x)@Q(w1)+b1)) ... see header analysis.
// Strategy: quantize to bf16 *grid values* (exact in bf16), GEMM in bf16 MFMA
// with fp32 accum, apply scale_a*scale_b in epilogue. Bit-exact quantization
// decisions vs jnp.searchsorted(side='left').

typedef __bf16 bf16_t;
typedef __bf16 bf16x8 __attribute__((ext_vector_type(8)));
typedef float f32x4 __attribute__((ext_vector_type(4)));

#define AS1 __attribute__((address_space(1)))
#define AS3 __attribute__((address_space(3)))

// ---------- quant helpers ----------
__device__ __forceinline__ float scale_from_amax_bits(unsigned bits) {
    return fmaxf(__uint_as_float(bits) / 6.0f, 1e-12f);
}

// nearest FP4(e2m1) grid point; ties round toward lower magnitude
// (matches np.searchsorted(mids, xs, side='left'))
__device__ __forceinline__ float quant_val(float v, float scale) {
    float xs = fabsf(v) / scale;
    float g = 0.0f;
    g = (xs > 0.25f) ? 0.5f : g;
    g = (xs > 0.75f) ? 1.0f : g;
    g = (xs > 1.25f) ? 1.5f : g;
    g = (xs > 1.75f) ? 2.0f : g;
    g = (xs > 2.5f)  ? 3.0f : g;
    g = (xs > 3.5f)  ? 4.0f : g;
    g = (xs > 5.0f)  ? 6.0f : g;
    return (v < 0.0f) ? -g : g;
}

// ---------- tiny utility kernels ----------
__global__ void zero4_kernel(unsigned* p) {
    if (threadIdx.x < 4) p[threadIdx.x] = 0u;
}

__global__ void sentinel_kernel(float* out, long long n) {
    long long i = (long long)blockIdx.x * blockDim.x + threadIdx.x;
    long long stride = (long long)gridDim.x * blockDim.x;
    for (; i < n; i += stride) out[i] = 1e30f;
}

// ---------- absmax reduction (n % 4 == 0) ----------
__global__ void absmax_kernel(const float* __restrict__ in, long long n,
                              unsigned* __restrict__ out) {
    long long i = ((long long)blockIdx.x * blockDim.x + threadIdx.x) * 4;
    long long stride = (long long)gridDim.x * blockDim.x * 4;
    float m = 0.0f;
    for (; i < n; i += stride) {
        float4 v = *(const float4*)&in[i];
        m = fmaxf(m, fmaxf(fmaxf(fabsf(v.x), fabsf(v.y)),
                           fmaxf(fabsf(v.z), fabsf(v.w))));
    }
    // butterfly wave reduce (64 lanes)
    #pragma unroll
    for (int off = 32; off > 0; off >>= 1)
        m = fmaxf(m, __shfl_xor(m, off));
    __shared__ float smax[4];
    int lane = threadIdx.x & 63, w = threadIdx.x >> 6;
    if (lane == 0) smax[w] = m;
    __syncthreads();
    if (threadIdx.x == 0) {
        m = fmaxf(fmaxf(smax[0], smax[1]), fmaxf(smax[2], smax[3]));
        atomicMax(out, __float_as_uint(m));  // valid: all values >= 0
    }
}

// ---------- elementwise quantize f32 -> bf16 grid values (n % 8 == 0) ----------
__global__ void quant_kernel(const float* __restrict__ in, long long n,
                             const unsigned* __restrict__ amax,
                             bf16_t* __restrict__ out) {
    float scale = scale_from_amax_bits(*amax);
    long long i = ((long long)blockIdx.x * blockDim.x + threadIdx.x) * 8;
    long long stride = (long long)gridDim.x * blockDim.x * 8;
    for (; i < n; i += stride) {
        float4 a = *(const float4*)&in[i];
        float4 b = *(const float4*)&in[i + 4];
        bf16x8 o;
        o[0] = (bf16_t)quant_val(a.x, scale);
        o[1] = (bf16_t)quant_val(a.y, scale);
        o[2] = (bf16_t)quant_val(a.z, scale);
        o[3] = (bf16_t)quant_val(a.w, scale);
        o[4] = (bf16_t)quant_val(b.x, scale);
        o[5] = (bf16_t)quant_val(b.y, scale);
        o[6] = (bf16_t)quant_val(b.z, scale);
        o[7] = (bf16_t)quant_val(b.w, scale);
        *(bf16x8*)&out[i] = o;
    }
}

// ---------- quantize + transpose: in [R][C] f32 -> out [C][R] bf16 ----------
// 64x64 tiles, 256 threads. R, C multiples of 64.
__global__ void quant_transpose_kernel(const float* __restrict__ in, int R, int C,
                                       const unsigned* __restrict__ amax,
                                       bf16_t* __restrict__ out) {
    __shared__ float tile[64][65];
    float scale = scale_from_amax_bits(*amax);
    int t = threadIdx.x;
    int CT = C >> 6;
    int tc = blockIdx.x % CT;
    int tr = blockIdx.x / CT;
    int r0 = t >> 4;            // 0..15
    int c0 = (t & 15) * 4;      // 0..60
    #pragma unroll
    for (int it = 0; it < 4; ++it) {
        int r = r0 + it * 16;
        float4 v = *(const float4*)&in[(size_t)(tr * 64 + r) * C + tc * 64 + c0];
        tile[r][c0 + 0] = v.x;
        tile[r][c0 + 1] = v.y;
        tile[r][c0 + 2] = v.z;
        tile[r][c0 + 3] = v.w;
    }
    __syncthreads();
    int c = t >> 2;             // 0..63 : output row (= input column)
    int rch = (t & 3) * 16;     // output col chunk
    bf16x8 o0, o1;
    #pragma unroll
    for (int j = 0; j < 8; ++j) o0[j] = (bf16_t)quant_val(tile[rch + j][c], scale);
    #pragma unroll
    for (int j = 0; j < 8; ++j) o1[j] = (bf16_t)quant_val(tile[rch + 8 + j][c], scale);
    size_t obase = (size_t)(tc * 64 + c) * R + tr * 64 + rch;
    *(bf16x8*)&out[obase] = o0;
    *(bf16x8*)&out[obase + 8] = o1;
}

// ---------- bf16 GEMM, C = (A @ BT^T) * (sa*sb) + bias, optional relu ----------
// A: [M][K] bf16 row-major; BT: [N][K] bf16 row-major; C: [M][N] f32.
// 128x128 tile, BK=32, 256 threads (2x2 waves of 64x64), mfma_f32_16x16x32_bf16.
// m97 structure: global_load_lds width-16 staging, 2 barriers per K-step.
template <int RELU>
__global__ __launch_bounds__(256, 2)
void gemm_bt_kernel(const bf16_t* __restrict__ A, const bf16_t* __restrict__ BT,
                    float* __restrict__ C, const float* __restrict__ bias,
                    const unsigned* __restrict__ amaxA,
                    const unsigned* __restrict__ amaxB,
                    int M, int N, int K) {
    __shared__ alignas(16) bf16_t As[128 * 32];
    __shared__ alignas(16) bf16_t Bs[128 * 32];

    // XCD-aware swizzle (gridDim.x % 8 == 0 by construction)
    int nwg = gridDim.x;
    int cpx = nwg >> 3;
    int wg = (blockIdx.x & 7) * cpx + (blockIdx.x >> 3);
    int MT = M >> 7;
    int tm = wg % MT;
    int tn = wg / MT;

    int tid = threadIdx.x;
    int lane = tid & 63;
    int wid = tid >> 6;                 // 0..3
    int wr = wid >> 1, wc = wid & 1;    // 2x2 wave grid, each owns 64x64

    // staging: wave `wid` loads 32 rows [wid*32, wid*32+32) of each 128x32 tile.
    // lane l covers row wid*32 + l/4, elements (l%4)*8 .. +8 (16 bytes).
    int srow = wid * 32 + (lane >> 2);
    int scol = (lane & 3) * 8;
    const bf16_t* Abase = A + (size_t)(tm * 128 + srow) * K + scol;
    const bf16_t* Bbase = BT + (size_t)(tn * 128 + srow) * K + scol;
    char* AsB = (char*)As;
    char* BsB = (char*)Bs;
    int ldsOffA = wid * 2048;           // 1024B per 16-row chunk, 2 chunks/wave

    f32x4 acc[4][4] = {};

    for (int kt = 0; kt < K; kt += 32) {
        __builtin_amdgcn_global_load_lds((const AS1 void*)(Abase + kt),
                                         (AS3 void*)(AsB + ldsOffA), 16, 0, 0);
        __builtin_amdgcn_global_load_lds((const AS1 void*)(Abase + kt + (size_t)16 * K),
                                         (AS3 void*)(AsB + ldsOffA + 1024), 16, 0, 0);
        __builtin_amdgcn_global_load_lds((const AS1 void*)(Bbase + kt),
                                         (AS3 void*)(BsB + ldsOffA), 16, 0, 0);
        __builtin_amdgcn_global_load_lds((const AS1 void*)(Bbase + kt + (size_t)16 * K),
                                         (AS3 void*)(BsB + ldsOffA + 1024), 16, 0, 0);
        __syncthreads();  // drains vmcnt(0) before barrier

        bf16x8 af[4], bff[4];
        #pragma unroll
        for (int mi = 0; mi < 4; ++mi)
            af[mi] = *(const bf16x8*)&As[(wr * 64 + mi * 16 + (lane & 15)) * 32 + (lane >> 4) * 8];
        #pragma unroll
        for (int ni = 0; ni < 4; ++ni)
            bff[ni] = *(const bf16x8*)&Bs[(wc * 64 + ni * 16 + (lane & 15)) * 32 + (lane >> 4) * 8];
        #pragma unroll
        for (int mi = 0; mi < 4; ++mi)
            #pragma unroll
            for (int ni = 0; ni < 4; ++ni)
                acc[mi][ni] = __builtin_amdgcn_mfma_f32_16x16x32_bf16(
                    af[mi], bff[ni], acc[mi][ni], 0, 0, 0);
        __syncthreads();  // compute done before next stage overwrites
    }

    float sa = scale_from_amax_bits(*amaxA);
    float sb = scale_from_amax_bits(*amaxB);
    float s = sa * sb;
    int rowBase = tm * 128 + wr * 64 + (lane >> 4) * 4;
    int colBase = tn * 128 + wc * 64 + (lane & 15);
    #pragma unroll
    for (int mi = 0; mi < 4; ++mi) {
        #pragma unroll
        for (int ni = 0; ni < 4; ++ni) {
            int col = colBase + ni * 16;
            float bv = bias[col];
            int row = rowBase + mi * 16;
            #pragma unroll
            for (int r = 0; r < 4; ++r) {
                float v = acc[mi][ni][r] * s + bv;
                if (RELU) v = fmaxf(v, 0.0f);
                C[(size_t)(row + r) * N + col] = v;
            }
        }
    }
}

// ---------- launch ----------
extern "C" void kernel_launch(void* const* d_in, const int* in_sizes, int n_in,
                              void* d_out, int out_size, void* d_ws, size_t ws_size,
                              hipStream_t stream) {
    const float* x  = (const float*)d_in[0];
    const float* w1 = (const float*)d_in[1];
    const float* b1 = (const float*)d_in[2];
    const float* w2 = (const float*)d_in[3];
    const float* b2 = (const float*)d_in[4];
    float* out = (float*)d_out;

    const int B = 4096, DIN = 4096, DH = 16384, DOUT = 4096;

    // workspace layout
    const size_t off_amax = 0;                                   // 4 uints
    const size_t off_Xq   = 256;                                 // 4096*4096*2
    const size_t off_W    = off_Xq + (size_t)B * DIN * 2;        // 134 MB (W1^T, then W2^T)
    const size_t off_h    = off_W + (size_t)DIN * DH * 2;        // 268 MB f32
    const size_t off_Hq   = off_h + (size_t)B * DH * 4;          // 134 MB
    const size_t needed   = off_Hq + (size_t)B * DH * 2;

    if (ws_size < needed) {
        // loud failure: sentinel so this is distinguishable from a math bug
        sentinel_kernel<<<2048, 256, 0, stream>>>(out, (long long)out_size);
        return;
    }

    char* ws = (char*)d_ws;
    unsigned* amax = (unsigned*)(ws + off_amax);  // [0]=x [1]=w1 [2]=h [3]=w2
    bf16_t* Xq = (bf16_t*)(ws + off_Xq);
    bf16_t* Wq = (bf16_t*)(ws + off_W);
    float*  h  = (float*)(ws + off_h);
    bf16_t* Hq = (bf16_t*)(ws + off_Hq);

    zero4_kernel<<<1, 64, 0, stream>>>(amax);

    absmax_kernel<<<2048, 256, 0, stream>>>(x, (long long)B * DIN, amax + 0);
    absmax_kernel<<<2048, 256, 0, stream>>>(w1, (long long)DIN * DH, amax + 1);
    absmax_kernel<<<2048, 256, 0, stream>>>(w2, (long long)DH * DOUT, amax + 3);

    quant_kernel<<<2048, 256, 0, stream>>>(x, (long long)B * DIN, amax + 0, Xq);
    quant_transpose_kernel<<<(DIN / 64) * (DH / 64), 256, 0, stream>>>(
        w1, DIN, DH, amax + 1, Wq);

    // h = relu(Q(x) @ Q(w1) + b1): M=4096, N=16384, K=4096
    gemm_bt_kernel<1><<<(B / 128) * (DH / 128), 256, 0, stream>>>(
        Xq, Wq, h, b1, amax + 0, amax + 1, B, DH, DIN);

    absmax_kernel<<<2048, 256, 0, stream>>>(h, (long long)B * DH, amax + 2);
    quant_kernel<<<2048, 256, 0, stream>>>(h, (long long)B * DH, amax + 2, Hq);
    quant_transpose_kernel<<<(DH / 64) * (DOUT / 64), 256, 0, stream>>>(
        w2, DH, DOUT, amax + 3, Wq);

    // out = Q(h) @ Q(w2) + b2: M=4096, N=4096, K=16384
    gemm_bt_kernel<0><<<(B / 128) * (DOUT / 128), 256, 0, stream>>>(
        Hq, Wq, out, b2, amax + 2, amax + 3, B, DOUT, DH);
}

// Round 2
// 691.164 us; speedup vs baseline: 3.0964x; 3.0964x over previous
//
#include <hip/hip_runtime.h>
#include <hip/hip_bf16.h>

// FP4 fake-quant MLP via REAL MX-FP4 MFMA.
// Quantized values are exactly the e2m1 grid {0,.5,1,1.5,2,3,4,6} * scale:
// pack the 4-bit codes, run mfma_scale_f32_16x16x128_f8f6f4 with unit block
// scales (0x7f), apply per-tensor scale_a*scale_b in the f32 epilogue.
// Products exact; only f32 accumulation order differs from reference.

typedef float f32x4 __attribute__((ext_vector_type(4)));
typedef int   i32x4 __attribute__((ext_vector_type(4)));
typedef int   i32x8 __attribute__((ext_vector_type(8)));

#define AS1 __attribute__((address_space(1)))
#define AS3 __attribute__((address_space(3)))

// ---------- quant helpers ----------
__device__ __forceinline__ float scale_from_amax_bits(unsigned bits) {
    return fmaxf(__uint_as_float(bits) / 6.0f, 1e-12f);
}

// FP4 e2m1 code: idx 0..7 over grid {0,.5,1,1.5,2,3,4,6}, sign in bit 3.
// Compare chain == np.searchsorted(mids, xs, side='left') (ties -> lower mag).
__device__ __forceinline__ unsigned q4(float v, float inv_scale) {
    float xs = fabsf(v) * inv_scale;
    unsigned idx = 0;
    idx += (xs > 0.25f);
    idx += (xs > 0.75f);
    idx += (xs > 1.25f);
    idx += (xs > 1.75f);
    idx += (xs > 2.5f);
    idx += (xs > 3.5f);
    idx += (xs > 5.0f);
    return idx | ((v < 0.0f) ? 8u : 0u);
}

// ---------- tiny utility kernels ----------
__global__ void zero4_kernel(unsigned* p) {
    if (threadIdx.x < 4) p[threadIdx.x] = 0u;
}

__global__ void sentinel_kernel(float* out, long long n) {
    long long i = (long long)blockIdx.x * blockDim.x + threadIdx.x;
    long long stride = (long long)gridDim.x * blockDim.x;
    for (; i < n; i += stride) out[i] = 1e30f;
}

// ---------- absmax reduction (n % 4 == 0) ----------
__global__ void absmax_kernel(const float* __restrict__ in, long long n,
                              unsigned* __restrict__ out) {
    long long i = ((long long)blockIdx.x * blockDim.x + threadIdx.x) * 4;
    long long stride = (long long)gridDim.x * blockDim.x * 4;
    float m = 0.0f;
    for (; i < n; i += stride) {
        float4 v = *(const float4*)&in[i];
        m = fmaxf(m, fmaxf(fmaxf(fabsf(v.x), fabsf(v.y)),
                           fmaxf(fabsf(v.z), fabsf(v.w))));
    }
    #pragma unroll
    for (int off = 32; off > 0; off >>= 1)
        m = fmaxf(m, __shfl_xor(m, off));
    __shared__ float smax[4];
    int lane = threadIdx.x & 63, w = threadIdx.x >> 6;
    if (lane == 0) smax[w] = m;
    __syncthreads();
    if (threadIdx.x == 0) {
        m = fmaxf(fmaxf(smax[0], smax[1]), fmaxf(smax[2], smax[3]));
        atomicMax(out, __float_as_uint(m));  // valid: all values >= 0
    }
}

// ---------- quantize f32 -> packed fp4 (n % 8 == 0), k-major nibbles ----------
__global__ void quant_pack_kernel(const float* __restrict__ in, long long n,
                                  const unsigned* __restrict__ amax,
                                  unsigned* __restrict__ out) {
    float inv = 1.0f / scale_from_amax_bits(*amax);
    long long i = ((long long)blockIdx.x * blockDim.x + threadIdx.x) * 8;
    long long stride = (long long)gridDim.x * blockDim.x * 8;
    for (; i < n; i += stride) {
        float4 a = *(const float4*)&in[i];
        float4 b = *(const float4*)&in[i + 4];
        unsigned u = q4(a.x, inv)        | (q4(a.y, inv) << 4)
                   | (q4(a.z, inv) << 8) | (q4(a.w, inv) << 12)
                   | (q4(b.x, inv) << 16)| (q4(b.y, inv) << 20)
                   | (q4(b.z, inv) << 24)| (q4(b.w, inv) << 28);
        out[i >> 3] = u;
    }
}

// ---------- quantize + transpose + pack: in [R][C] f32 -> out [C][R/2] bytes --
// 64x64 tiles, 256 threads. R, C multiples of 64.
__global__ void quant_transpose_pack_kernel(const float* __restrict__ in, int R, int C,
                                            const unsigned* __restrict__ amax,
                                            unsigned char* __restrict__ out) {
    __shared__ float tile[64][65];
    float inv = 1.0f / scale_from_amax_bits(*amax);
    int t = threadIdx.x;
    int CT = C >> 6;
    int tc = blockIdx.x % CT;
    int tr = blockIdx.x / CT;
    int r0 = t >> 4;            // 0..15
    int c0 = (t & 15) * 4;      // 0..60
    #pragma unroll
    for (int it = 0; it < 4; ++it) {
        int r = r0 + it * 16;
        float4 v = *(const float4*)&in[(size_t)(tr * 64 + r) * C + tc * 64 + c0];
        tile[r][c0 + 0] = v.x;
        tile[r][c0 + 1] = v.y;
        tile[r][c0 + 2] = v.z;
        tile[r][c0 + 3] = v.w;
    }
    __syncthreads();
    int c = t >> 2;             // 0..63 : output row (= input column)
    int rch = (t & 3) * 16;     // k-chunk of 16 values (k0 even)
    unsigned u0 = 0, u1 = 0;
    #pragma unroll
    for (int j = 0; j < 8; ++j) u0 |= q4(tile[rch + j][c], inv) << (4 * j);
    #pragma unroll
    for (int j = 0; j < 8; ++j) u1 |= q4(tile[rch + 8 + j][c], inv) << (4 * j);
    uint2 o; o.x = u0; o.y = u1;
    *(uint2*)&out[(size_t)(tc * 64 + c) * (R >> 1) + (size_t)(tr * 32) + (rch >> 1)] = o;
}

// ---------- FP4 GEMM: C = (A @ BT^T) * (sa*sb) + bias, optional relu/amax ----
// Ap: [M][K/2] bytes (fp4 k-major); Bp: [N][K/2]; C: [M][N] f32.
// 128x128 tile, BK=256 fp4 (128B/row), 256 threads (2x2 waves of 64x64).
// mfma_scale_f32_16x16x128_f8f6f4, cbsz=blgp=4 (fp4), unit block scales.
// LDS: linear dest for global_load_lds; XOR chunk swizzle (chunk ^= row&7)
// applied on BOTH the global source address and the ds_read (rule #21).
template <int RELU, int FUSE_AMAX>
__global__ __launch_bounds__(256, 2)
void gemm_fp4_kernel(const unsigned char* __restrict__ Ap,
                     const unsigned char* __restrict__ Bp,
                     float* __restrict__ C, const float* __restrict__ bias,
                     const unsigned* __restrict__ amaxA,
                     const unsigned* __restrict__ amaxB,
                     unsigned* __restrict__ amaxOut,
                     int M, int N, int K) {
    __shared__ alignas(16) unsigned char As[128 * 128];  // 16 KB
    __shared__ alignas(16) unsigned char Bs[128 * 128];  // 16 KB
    __shared__ float smax[4];

    // XCD-aware swizzle (gridDim.x % 8 == 0 by construction)
    int nwg = gridDim.x;
    int cpx = nwg >> 3;
    int wg = (blockIdx.x & 7) * cpx + (blockIdx.x >> 3);
    int MT = M >> 7;
    int tm = wg % MT;
    int tn = wg / MT;

    int tid = threadIdx.x;
    int lane = tid & 63;
    int wid = tid >> 6;                 // 0..3
    int wr = wid >> 1, wc = wid & 1;    // 2x2 wave grid, each owns 64x64

    size_t Kb = (size_t)(K >> 1);       // bytes per packed row

    // Staging: per K-tile each matrix tile is 128 rows x 128B. One instr:
    // 64 lanes x 16B = 8 rows; lane covers row (lane>>3), chunk (lane&7).
    // Global source chunk is pre-swizzled: cs = (lane&7) ^ (row&7), and
    // row&7 == (lane>>3)&7 for every instr (row base is a multiple of 8).
    int cs = ((lane & 7) ^ ((lane >> 3) & 7)) << 4;
    int srow = wid * 32 + (lane >> 3);
    const unsigned char* Abase = Ap + (size_t)(tm * 128 + srow) * Kb + cs;
    const unsigned char* Bbase = Bp + (size_t)(tn * 128 + srow) * Kb + cs;
    char* AsB = (char*)As;
    char* BsB = (char*)Bs;
    int ldsOff = wid * 4096;            // wave's 32 rows x 128B

    f32x4 acc[4][4] = {};

    int rrA = wr * 64 + (lane & 15);    // fragment row in A tile (+ mi*16)
    int rrB = wc * 64 + (lane & 15);    // fragment row in B tile (+ ni*16)

    int KT = K >> 8;                    // K-tiles of 256 fp4
    for (int kt = 0; kt < KT; ++kt) {
        #pragma unroll
        for (int i = 0; i < 4; ++i) {
            __builtin_amdgcn_global_load_lds(
                (const AS1 void*)(Abase + (size_t)kt * 128 + (size_t)(i * 8) * Kb),
                (AS3 void*)(AsB + ldsOff + i * 1024), 16, 0, 0);
            __builtin_amdgcn_global_load_lds(
                (const AS1 void*)(Bbase + (size_t)kt * 128 + (size_t)(i * 8) * Kb),
                (AS3 void*)(BsB + ldsOff + i * 1024), 16, 0, 0);
        }
        __syncthreads();  // compiler drains vmcnt(0) before barrier

        #pragma unroll
        for (int ks = 0; ks < 2; ++ks) {
            // global 16B-chunk index within the row: ks*4 + (lane>>4);
            // LDS slot = chunk ^ (row&7), row&7 == lane&7 for all mi/ni.
            int slotOff = ((ks * 4 + (lane >> 4)) ^ (lane & 7)) << 4;
            i32x8 a8[4], b8[4];
            #pragma unroll
            for (int mi = 0; mi < 4; ++mi) {
                i32x4 v = *(const i32x4*)(AsB + (rrA + mi * 16) * 128 + slotOff);
                a8[mi] = i32x8{v[0], v[1], v[2], v[3], 0, 0, 0, 0};
            }
            #pragma unroll
            for (int ni = 0; ni < 4; ++ni) {
                i32x4 v = *(const i32x4*)(BsB + (rrB + ni * 16) * 128 + slotOff);
                b8[ni] = i32x8{v[0], v[1], v[2], v[3], 0, 0, 0, 0};
            }
            #pragma unroll
            for (int mi = 0; mi < 4; ++mi)
                #pragma unroll
                for (int ni = 0; ni < 4; ++ni)
                    acc[mi][ni] = __builtin_amdgcn_mfma_scale_f32_16x16x128_f8f6f4(
                        a8[mi], b8[ni], acc[mi][ni],
                        4, 4,                    // cbsz=fp4, blgp=fp4
                        0, 0x7f7f7f7f,           // scale_a opsel, E8M0 1.0
                        0, 0x7f7f7f7f);          // scale_b opsel, E8M0 1.0
        }
        __syncthreads();
    }

    float sa = scale_from_amax_bits(*amaxA);
    float sb = scale_from_amax_bits(*amaxB);
    float s = sa * sb;
    float vmax = 0.0f;
    int rowBase = tm * 128 + wr * 64 + (lane >> 4) * 4;
    int colBase = tn * 128 + wc * 64 + (lane & 15);
    #pragma unroll
    for (int mi = 0; mi < 4; ++mi) {
        #pragma unroll
        for (int ni = 0; ni < 4; ++ni) {
            int col = colBase + ni * 16;
            float bv = bias[col];
            int row = rowBase + mi * 16;
            #pragma unroll
            for (int r = 0; r < 4; ++r) {
                float v = acc[mi][ni][r] * s + bv;
                if (RELU) v = fmaxf(v, 0.0f);
                if (FUSE_AMAX) vmax = fmaxf(vmax, fabsf(v));
                C[(size_t)(row + r) * N + col] = v;
            }
        }
    }
    if (FUSE_AMAX) {
        #pragma unroll
        for (int off = 32; off > 0; off >>= 1)
            vmax = fmaxf(vmax, __shfl_xor(vmax, off));
        if (lane == 0) smax[wid] = vmax;
        __syncthreads();
        if (tid == 0) {
            vmax = fmaxf(fmaxf(smax[0], smax[1]), fmaxf(smax[2], smax[3]));
            atomicMax(amaxOut, __float_as_uint(vmax));
        }
    }
}

// ---------- launch ----------
extern "C" void kernel_launch(void* const* d_in, const int* in_sizes, int n_in,
                              void* d_out, int out_size, void* d_ws, size_t ws_size,
                              hipStream_t stream) {
    const float* x  = (const float*)d_in[0];
    const float* w1 = (const float*)d_in[1];
    const float* b1 = (const float*)d_in[2];
    const float* w2 = (const float*)d_in[3];
    const float* b2 = (const float*)d_in[4];
    float* out = (float*)d_out;

    const int B = 4096, DIN = 4096, DH = 16384, DOUT = 4096;

    // workspace layout (packed fp4 operands)
    const size_t off_amax = 0;                                    // 4 uints
    const size_t off_Xq   = 256;                                  // 8 MB
    const size_t off_W    = off_Xq + (size_t)B * DIN / 2;         // 32 MB (w1^T then w2^T)
    const size_t off_h    = off_W + (size_t)DIN * DH / 2;         // 256 MB f32
    const size_t off_Hq   = off_h + (size_t)B * DH * 4;           // 32 MB
    const size_t needed   = off_Hq + (size_t)B * DH / 2;

    if (ws_size < needed) {
        sentinel_kernel<<<2048, 256, 0, stream>>>(out, (long long)out_size);
        return;
    }

    char* ws = (char*)d_ws;
    unsigned* amax = (unsigned*)(ws + off_amax);  // [0]=x [1]=w1 [2]=h [3]=w2
    unsigned char* Xq = (unsigned char*)(ws + off_Xq);
    unsigned char* Wq = (unsigned char*)(ws + off_W);
    float*         h  = (float*)(ws + off_h);
    unsigned char* Hq = (unsigned char*)(ws + off_Hq);

    zero4_kernel<<<1, 64, 0, stream>>>(amax);

    absmax_kernel<<<2048, 256, 0, stream>>>(x, (long long)B * DIN, amax + 0);
    absmax_kernel<<<2048, 256, 0, stream>>>(w1, (long long)DIN * DH, amax + 1);
    absmax_kernel<<<2048, 256, 0, stream>>>(w2, (long long)DH * DOUT, amax + 3);

    quant_pack_kernel<<<2048, 256, 0, stream>>>(x, (long long)B * DIN, amax + 0,
                                                (unsigned*)Xq);
    quant_transpose_pack_kernel<<<(DIN / 64) * (DH / 64), 256, 0, stream>>>(
        w1, DIN, DH, amax + 1, Wq);

    // h = relu(Q(x) @ Q(w1) + b1), fused absmax(h) -> amax[2]
    gemm_fp4_kernel<1, 1><<<(B / 128) * (DH / 128), 256, 0, stream>>>(
        Xq, Wq, h, b1, amax + 0, amax + 1, amax + 2, B, DH, DIN);

    quant_pack_kernel<<<2048, 256, 0, stream>>>(h, (long long)B * DH, amax + 2,
                                                (unsigned*)Hq);
    quant_transpose_pack_kernel<<<(DH / 64) * (DOUT / 64), 256, 0, stream>>>(
        w2, DH, DOUT, amax + 3, Wq);

    // out = Q(h) @ Q(w2) + b2
    gemm_fp4_kernel<0, 0><<<(B / 128) * (DOUT / 128), 256, 0, stream>>>(
        Hq, Wq, out, b2, amax + 2, amax + 3, nullptr, B, DOUT, DH);
}